// Round 1
// baseline (322.173 us; speedup 1.0000x reference)
//
#include <hip/hip_runtime.h>
#include <hip/hip_bf16.h>
#include <stdint.h>

#define Bdim 2
#define Sdim 2048
#define Ddim 1024
#define Hdim 16
#define DHdim 64
#define Mdim (Bdim*Sdim)   // 4096

typedef short short8 __attribute__((ext_vector_type(8)));
typedef float f32x4 __attribute__((ext_vector_type(4)));

__device__ __forceinline__ uint16_t f2b(float f) {
  union { float f; uint32_t u; } c; c.f = f;
  uint32_t u = c.u;
  u += 0x7fffu + ((u >> 16) & 1u);   // RNE
  return (uint16_t)(u >> 16);
}

__device__ __forceinline__ void gl_lds16(const void* g, void* l) {
  __builtin_amdgcn_global_load_lds(
      (const __attribute__((address_space(1))) void*)g,
      (__attribute__((address_space(3))) void*)l, 16, 0, 0);
}

// ---------------- f32 -> bf16 conversion ----------------
__global__ void cvt_bf16(const float* __restrict__ in, uint16_t* __restrict__ out) {
  int i = (blockIdx.x * 256 + threadIdx.x) * 4;
  float4 v = *(const float4*)(in + i);
  ushort4 o;
  o.x = f2b(v.x); o.y = f2b(v.y); o.z = f2b(v.z); o.w = f2b(v.w);
  *(ushort4*)(out + i) = o;
}

// ---------------- shared 128x128 GEMM mainloop (C = A * B^T), bf16 ----------------
// A: MxK row-major, Bm: NxK row-major, both bf16. BK=32. 256 threads = 4 waves (2x2).
__device__ __forceinline__ void gemm_tile_128(
    const uint16_t* __restrict__ A, const uint16_t* __restrict__ Bm,
    int K, int row0, int col0, uint16_t* lds, f32x4 acc[4][4])
{
  uint16_t* As = lds;            // [128][32]
  uint16_t* Bs = lds + 128*32;   // [128][32]
  const int t = threadIdx.x;
  const int lane = t & 63;
  const int w = t >> 6;
  const int wr = (w >> 1) * 64;
  const int wc = (w & 1) * 64;
  const int fr = lane & 15;
  const int fk = (lane >> 4) * 8;

  for (int k0 = 0; k0 < K; k0 += 32) {
#pragma unroll
    for (int i = 0; i < 2; ++i) {
      int e = (i*256 + t) * 8;
      int r = e >> 5, c = e & 31;
      gl_lds16(A  + (size_t)(row0 + r) * K + (k0 + c), As + e);
      gl_lds16(Bm + (size_t)(col0 + r) * K + (k0 + c), Bs + e);
    }
    __syncthreads();
    short8 af[4], bf[4];
#pragma unroll
    for (int m = 0; m < 4; ++m)
      af[m] = *(const short8*)(As + (wr + m*16 + fr)*32 + fk);
#pragma unroll
    for (int n = 0; n < 4; ++n)
      bf[n] = *(const short8*)(Bs + (wc + n*16 + fr)*32 + fk);
#pragma unroll
    for (int m = 0; m < 4; ++m)
#pragma unroll
      for (int n = 0; n < 4; ++n)
        acc[m][n] = __builtin_amdgcn_mfma_f32_16x16x32_bf16(af[m], bf[n], acc[m][n], 0, 0, 0);
    __syncthreads();
  }
}

// ---------------- fused QKV projection ----------------
// grid (24, 32): x = [grp(3) x coltile(8)], y = row tile. Writes head-split bf16.
// Q pre-scaled by 1/sqrt(DH). V written transposed (B,H,DH,S).
__global__ __launch_bounds__(256, 2) void gemm_qkv(
    const uint16_t* __restrict__ xq, const uint16_t* __restrict__ xkv,
    const uint16_t* __restrict__ Wq, const uint16_t* __restrict__ Wk,
    const uint16_t* __restrict__ Wv,
    const float* __restrict__ bq, const float* __restrict__ bk,
    const float* __restrict__ bv,
    uint16_t* __restrict__ Qo, uint16_t* __restrict__ Ko, uint16_t* __restrict__ Vo)
{
  __shared__ uint16_t lds[2*128*32];
  const int grp  = blockIdx.x >> 3;
  const int col0 = (blockIdx.x & 7) * 128;
  const int row0 = blockIdx.y * 128;
  const uint16_t* A  = (grp == 0) ? xq : xkv;
  const uint16_t* Wm = (grp == 0) ? Wq : (grp == 1) ? Wk : Wv;
  const float* bias  = (grp == 0) ? bq : (grp == 1) ? bk : bv;
  uint16_t* out      = (grp == 0) ? Qo : (grp == 1) ? Ko : Vo;

  f32x4 acc[4][4] = {};
  gemm_tile_128(A, Wm, Ddim, row0, col0, lds, acc);

  const int lane = threadIdx.x & 63;
  const int w = threadIdx.x >> 6;
  const int wr = (w >> 1) * 64, wc = (w & 1) * 64;
  const float scale = (grp == 0) ? 0.125f : 1.0f;
#pragma unroll
  for (int n = 0; n < 4; ++n) {
    const int j  = col0 + wc + n*16 + (lane & 15);
    const float bj = bias[j];
    const int h = j >> 6, dh = j & 63;
#pragma unroll
    for (int m = 0; m < 4; ++m) {
      const int rbase = row0 + wr + m*16 + (lane >> 4) * 4;
#pragma unroll
      for (int r = 0; r < 4; ++r) {
        const int i = rbase + r;
        const int b = i >> 11, s = i & 2047;
        float v = (acc[m][n][r] + bj) * scale;
        size_t addr;
        if (grp == 2) addr = ((size_t)(b*Hdim + h)) * (DHdim*Sdim) + (size_t)dh * Sdim + s;
        else          addr = ((size_t)(b*Hdim + h)) * (Sdim*DHdim) + (size_t)s * DHdim + dh;
        out[addr] = f2b(v);
      }
    }
  }
}

// ---------------- flash attention ----------------
// grid (32, 32): x = q-tile (64 rows), y = b*H+h. 4 waves x 16 q-rows.
__global__ __launch_bounds__(256, 2) void attn(
    const uint16_t* __restrict__ Q, const uint16_t* __restrict__ K,
    const uint16_t* __restrict__ V, uint16_t* __restrict__ AO)
{
  __shared__ uint16_t Qs[64*64];
  __shared__ uint16_t Ks[64*64];
  __shared__ uint16_t Vs[64*64];   // V^T tile: [dh][key]
  __shared__ uint16_t Ps[64*64];
  const int t = threadIdx.x, lane = t & 63, w = t >> 6;
  const int bh = blockIdx.y, qt = blockIdx.x;
  const uint16_t* Qh = Q + (size_t)bh * (Sdim*DHdim) + qt * (64*DHdim);
  const uint16_t* Kh = K + (size_t)bh * (Sdim*DHdim);
  const uint16_t* Vh = V + (size_t)bh * (DHdim*Sdim);

#pragma unroll
  for (int i = 0; i < 2; ++i) {
    int e = (i*256 + t) * 8;
    gl_lds16(Qh + e, Qs + e);
  }
  __syncthreads();
  const int fr = lane & 15, fk = (lane >> 4) * 8;
  short8 qf0 = *(const short8*)(Qs + (w*16 + fr)*64 + fk);
  short8 qf1 = *(const short8*)(Qs + (w*16 + fr)*64 + 32 + fk);

  float m_run[4], l_run[4];
  f32x4 oacc[4] = {};
#pragma unroll
  for (int r = 0; r < 4; ++r) { m_run[r] = -1e30f; l_run[r] = 0.f; }

  for (int kt = 0; kt < Sdim/64; ++kt) {
#pragma unroll
    for (int i = 0; i < 2; ++i) {
      int e = (i*256 + t) * 8;
      gl_lds16(Kh + (size_t)kt*64*DHdim + e, Ks + e);
      int vr = e >> 6, vc = e & 63;
      gl_lds16(Vh + (size_t)vr * Sdim + kt*64 + vc, Vs + e);
    }
    __syncthreads();

    f32x4 sc[4];
#pragma unroll
    for (int kf = 0; kf < 4; ++kf) {
      short8 kb0 = *(const short8*)(Ks + (kf*16 + fr)*64 + fk);
      short8 kb1 = *(const short8*)(Ks + (kf*16 + fr)*64 + 32 + fk);
      f32x4 z = {};
      z = __builtin_amdgcn_mfma_f32_16x16x32_bf16(qf0, kb0, z, 0, 0, 0);
      sc[kf] = __builtin_amdgcn_mfma_f32_16x16x32_bf16(qf1, kb1, z, 0, 0, 0);
    }

    // online softmax: lane holds rows (lane>>4)*4+r, col kf*16+(lane&15)
    float tm[4];
#pragma unroll
    for (int r = 0; r < 4; ++r)
      tm[r] = fmaxf(fmaxf(sc[0][r], sc[1][r]), fmaxf(sc[2][r], sc[3][r]));
#pragma unroll
    for (int d = 1; d < 16; d <<= 1)
#pragma unroll
      for (int r = 0; r < 4; ++r)
        tm[r] = fmaxf(tm[r], __shfl_xor(tm[r], d, 64));
    float al[4], rs[4];
#pragma unroll
    for (int r = 0; r < 4; ++r) {
      float mn = fmaxf(m_run[r], tm[r]);
      al[r] = __expf(m_run[r] - mn);
      m_run[r] = mn;
      rs[r] = 0.f;
    }
#pragma unroll
    for (int kf = 0; kf < 4; ++kf)
#pragma unroll
      for (int r = 0; r < 4; ++r) {
        float p = __expf(sc[kf][r] - m_run[r]);
        sc[kf][r] = p;
        rs[r] += p;
      }
#pragma unroll
    for (int d = 1; d < 16; d <<= 1)
#pragma unroll
      for (int r = 0; r < 4; ++r)
        rs[r] += __shfl_xor(rs[r], d, 64);
#pragma unroll
    for (int r = 0; r < 4; ++r)
      l_run[r] = l_run[r] * al[r] + rs[r];
#pragma unroll
    for (int df = 0; df < 4; ++df)
#pragma unroll
      for (int r = 0; r < 4; ++r)
        oacc[df][r] *= al[r];

    // P (C-layout) -> LDS -> A-layout. Region is wave-private; barrier for ordering.
#pragma unroll
    for (int kf = 0; kf < 4; ++kf)
#pragma unroll
      for (int r = 0; r < 4; ++r)
        Ps[(w*16 + (lane>>4)*4 + r)*64 + kf*16 + fr] = f2b(sc[kf][r]);
    __syncthreads();
    short8 pf0 = *(const short8*)(Ps + (w*16 + fr)*64 + fk);
    short8 pf1 = *(const short8*)(Ps + (w*16 + fr)*64 + 32 + fk);
#pragma unroll
    for (int df = 0; df < 4; ++df) {
      short8 vb0 = *(const short8*)(Vs + (df*16 + fr)*64 + fk);
      short8 vb1 = *(const short8*)(Vs + (df*16 + fr)*64 + 32 + fk);
      oacc[df] = __builtin_amdgcn_mfma_f32_16x16x32_bf16(pf0, vb0, oacc[df], 0, 0, 0);
      oacc[df] = __builtin_amdgcn_mfma_f32_16x16x32_bf16(pf1, vb1, oacc[df], 0, 0, 0);
    }
    __syncthreads();
  }

  // epilogue -> attn_out (B,S,D) bf16
  const int b = bh >> 4, h = bh & 15;
#pragma unroll
  for (int df = 0; df < 4; ++df) {
    const int d = df*16 + fr;
#pragma unroll
    for (int r = 0; r < 4; ++r) {
      const int srow = qt*64 + w*16 + (lane>>4)*4 + r;
      float o = oacc[df][r] / l_run[r];
      AO[((size_t)b * Sdim + srow) * Ddim + h*DHdim + d] = f2b(o);
    }
  }
}

// ---------------- output projection (f32 out + bias) ----------------
__global__ __launch_bounds__(256, 2) void gemm_out(
    const uint16_t* __restrict__ AOb, const uint16_t* __restrict__ Wo,
    const float* __restrict__ bo, float* __restrict__ out)
{
  __shared__ uint16_t lds[2*128*32];
  const int col0 = blockIdx.x * 128;
  const int row0 = blockIdx.y * 128;
  f32x4 acc[4][4] = {};
  gemm_tile_128(AOb, Wo, Ddim, row0, col0, lds, acc);
  const int lane = threadIdx.x & 63;
  const int w = threadIdx.x >> 6;
  const int wr = (w >> 1) * 64, wc = (w & 1) * 64;
#pragma unroll
  for (int n = 0; n < 4; ++n) {
    const int j = col0 + wc + n*16 + (lane & 15);
    const float bj = bo[j];
#pragma unroll
    for (int m = 0; m < 4; ++m) {
      const int rbase = row0 + wr + m*16 + (lane >> 4) * 4;
#pragma unroll
      for (int r = 0; r < 4; ++r)
        out[(size_t)(rbase + r) * Ddim + j] = acc[m][n][r] + bj;
    }
  }
}

extern "C" void kernel_launch(void* const* d_in, const int* in_sizes, int n_in,
                              void* d_out, int out_size, void* d_ws, size_t ws_size,
                              hipStream_t stream) {
  (void)in_sizes; (void)n_in; (void)out_size; (void)ws_size;
  const float* xq  = (const float*)d_in[0];
  const float* xkv = (const float*)d_in[1];
  const float* Wq  = (const float*)d_in[2];
  const float* bq  = (const float*)d_in[3];
  const float* Wk  = (const float*)d_in[4];
  const float* bk  = (const float*)d_in[5];
  const float* Wv  = (const float*)d_in[6];
  const float* bv  = (const float*)d_in[7];
  const float* Wo  = (const float*)d_in[8];
  const float* bo  = (const float*)d_in[9];
  float* out = (float*)d_out;

  uint16_t* ws = (uint16_t*)d_ws;
  const size_t NX = (size_t)Mdim * Ddim;   // 4194304
  const size_t NW = (size_t)Ddim * Ddim;   // 1048576
  uint16_t* xq_b  = ws; ws += NX;
  uint16_t* xkv_b = ws; ws += NX;
  uint16_t* wq_b  = ws; ws += NW;
  uint16_t* wk_b  = ws; ws += NW;
  uint16_t* wv_b  = ws; ws += NW;
  uint16_t* wo_b  = ws; ws += NW;
  uint16_t* Qb    = ws; ws += NX;
  uint16_t* Kb    = ws; ws += NX;
  uint16_t* Vb    = ws; ws += NX;
  uint16_t* AOb   = ws; ws += NX;

  cvt_bf16<<<NX/1024, 256, 0, stream>>>(xq,  xq_b);
  cvt_bf16<<<NX/1024, 256, 0, stream>>>(xkv, xkv_b);
  cvt_bf16<<<NW/1024, 256, 0, stream>>>(Wq,  wq_b);
  cvt_bf16<<<NW/1024, 256, 0, stream>>>(Wk,  wk_b);
  cvt_bf16<<<NW/1024, 256, 0, stream>>>(Wv,  wv_b);
  cvt_bf16<<<NW/1024, 256, 0, stream>>>(Wo,  wo_b);

  gemm_qkv<<<dim3(24, 32), 256, 0, stream>>>(xq_b, xkv_b, wq_b, wk_b, wv_b,
                                             bq, bk, bv, Qb, Kb, Vb);
  attn<<<dim3(32, 32), 256, 0, stream>>>(Qb, Kb, Vb, AOb);
  gemm_out<<<dim3(8, 32), 256, 0, stream>>>(AOb, wo_b, bo, out);
}

// Round 3
// 273.439 us; speedup vs baseline: 1.1782x; 1.1782x over previous
//
#include <hip/hip_runtime.h>
#include <hip/hip_bf16.h>
#include <stdint.h>

#define Bdim 2
#define Sdim 2048
#define Ddim 1024
#define Hdim 16
#define DHdim 64
#define Mdim (Bdim*Sdim)   // 4096

typedef short short8 __attribute__((ext_vector_type(8)));
typedef float f32x4 __attribute__((ext_vector_type(4)));

__device__ __forceinline__ uint16_t f2b(float f) {
  union { float f; uint32_t u; } c; c.f = f;
  uint32_t u = c.u;
  u += 0x7fffu + ((u >> 16) & 1u);   // RNE
  return (uint16_t)(u >> 16);
}

__device__ __forceinline__ void gl_lds16(const void* g, void* l) {
  __builtin_amdgcn_global_load_lds(
      (const __attribute__((address_space(1))) void*)g,
      (__attribute__((address_space(3))) void*)l, 16, 0, 0);
}

// XOR swizzle for [row][64]-elem bf16 tiles: 16B slot index ^= row&7.
// Involution; keeps 8-elem (16B) runs contiguous.
__device__ __forceinline__ int swz(int e) {
  return e ^ (((e >> 6) & 7) << 3);
}
__device__ __forceinline__ int lswz(int row, int col) {
  return row * 64 + (col ^ ((row & 7) << 3));
}

// ---------------- f32 -> bf16 conversion ----------------
__global__ void cvt_bf16(const float* __restrict__ in, uint16_t* __restrict__ out) {
  int i = (blockIdx.x * 256 + threadIdx.x) * 4;
  float4 v = *(const float4*)(in + i);
  ushort4 o;
  o.x = f2b(v.x); o.y = f2b(v.y); o.z = f2b(v.z); o.w = f2b(v.w);
  *(ushort4*)(out + i) = o;
}

// ---------------- shared 128x128 GEMM mainloop (C = A * B^T), bf16 ----------------
__device__ __forceinline__ void gemm_tile_128(
    const uint16_t* __restrict__ A, const uint16_t* __restrict__ Bm,
    int K, int row0, int col0, uint16_t* lds, f32x4 acc[4][4])
{
  uint16_t* As = lds;            // [128][32]
  uint16_t* Bs = lds + 128*32;   // [128][32]
  const int t = threadIdx.x;
  const int lane = t & 63;
  const int w = t >> 6;
  const int wr = (w >> 1) * 64;
  const int wc = (w & 1) * 64;
  const int fr = lane & 15;
  const int fk = (lane >> 4) * 8;

  for (int k0 = 0; k0 < K; k0 += 32) {
#pragma unroll
    for (int i = 0; i < 2; ++i) {
      int e = (i*256 + t) * 8;
      int r = e >> 5, c = e & 31;
      gl_lds16(A  + (size_t)(row0 + r) * K + (k0 + c), As + e);
      gl_lds16(Bm + (size_t)(col0 + r) * K + (k0 + c), Bs + e);
    }
    __syncthreads();
    short8 af[4], bf[4];
#pragma unroll
    for (int m = 0; m < 4; ++m)
      af[m] = *(const short8*)(As + (wr + m*16 + fr)*32 + fk);
#pragma unroll
    for (int n = 0; n < 4; ++n)
      bf[n] = *(const short8*)(Bs + (wc + n*16 + fr)*32 + fk);
#pragma unroll
    for (int m = 0; m < 4; ++m)
#pragma unroll
      for (int n = 0; n < 4; ++n)
        acc[m][n] = __builtin_amdgcn_mfma_f32_16x16x32_bf16(af[m], bf[n], acc[m][n], 0, 0, 0);
    __syncthreads();
  }
}

// ---------------- fused QKV projection ----------------
__global__ __launch_bounds__(256, 2) void gemm_qkv(
    const uint16_t* __restrict__ xq, const uint16_t* __restrict__ xkv,
    const uint16_t* __restrict__ Wq, const uint16_t* __restrict__ Wk,
    const uint16_t* __restrict__ Wv,
    const float* __restrict__ bq, const float* __restrict__ bk,
    const float* __restrict__ bv,
    uint16_t* __restrict__ Qo, uint16_t* __restrict__ Ko, uint16_t* __restrict__ Vo)
{
  __shared__ uint16_t lds[2*128*32];
  const int grp  = blockIdx.x >> 3;
  const int col0 = (blockIdx.x & 7) * 128;
  const int row0 = blockIdx.y * 128;
  const uint16_t* A  = (grp == 0) ? xq : xkv;
  const uint16_t* Wm = (grp == 0) ? Wq : (grp == 1) ? Wk : Wv;
  const float* bias  = (grp == 0) ? bq : (grp == 1) ? bk : bv;

  f32x4 acc[4][4] = {};
  gemm_tile_128(A, Wm, Ddim, row0, col0, lds, acc);

  const int lane = threadIdx.x & 63;
  const int w = threadIdx.x >> 6;
  const int wr = (w >> 1) * 64, wc = (w & 1) * 64;

  if (grp == 2) {
    // V -> (B,H,DH,S), packed 4-consecutive-s stores
#pragma unroll
    for (int n = 0; n < 4; ++n) {
      const int j  = col0 + wc + n*16 + (lane & 15);
      const float bj = bias[j];
      const int h = j >> 6, dh = j & 63;
#pragma unroll
      for (int m = 0; m < 4; ++m) {
        const int rbase = row0 + wr + m*16 + (lane >> 4) * 4;
        const int b = rbase >> 11, s = rbase & 2047;
        ushort4 o;
        o.x = f2b(acc[m][n][0] + bj);
        o.y = f2b(acc[m][n][1] + bj);
        o.z = f2b(acc[m][n][2] + bj);
        o.w = f2b(acc[m][n][3] + bj);
        *(ushort4*)(Vo + ((size_t)(b*Hdim + h)) * (DHdim*Sdim) + (size_t)dh * Sdim + s) = o;
      }
    }
  } else {
    uint16_t* out = (grp == 0) ? Qo : Ko;
    const float scale = (grp == 0) ? 0.125f : 1.0f;
#pragma unroll
    for (int n = 0; n < 4; ++n) {
      const int j  = col0 + wc + n*16 + (lane & 15);
      const float bj = bias[j];
      const int h = j >> 6, dh = j & 63;
#pragma unroll
      for (int m = 0; m < 4; ++m) {
        const int rbase = row0 + wr + m*16 + (lane >> 4) * 4;
#pragma unroll
        for (int r = 0; r < 4; ++r) {
          const int i = rbase + r;
          const int b = i >> 11, s = i & 2047;
          float v = (acc[m][n][r] + bj) * scale;
          out[((size_t)(b*Hdim + h)) * (Sdim*DHdim) + (size_t)s * DHdim + dh] = f2b(v);
        }
      }
    }
  }
}

// ---------------- flash attention ----------------
// grid (32, 32): x = q-tile (64 rows), y = b*H+h. 4 waves x 16 q-rows.
// LDS: QPs (Q, reused as P) + K dbuf + V dbuf, all XOR-swizzled. 40 KB.
__global__ __launch_bounds__(256, 4) void attn(
    const uint16_t* __restrict__ Q, const uint16_t* __restrict__ K,
    const uint16_t* __restrict__ V, uint16_t* __restrict__ AO)
{
  __shared__ uint16_t lds[5*64*64];
  uint16_t* QPs = lds;                 // Q tile, reused as P after prologue
  const int t = threadIdx.x, lane = t & 63, w = t >> 6;
  const int bh = blockIdx.y, qt = blockIdx.x;
  const uint16_t* Qh = Q + (size_t)bh * (Sdim*DHdim) + qt * (64*DHdim);
  const uint16_t* Kh = K + (size_t)bh * (Sdim*DHdim);
  const uint16_t* Vh = V + (size_t)bh * (DHdim*Sdim);
  const int fr = lane & 15, fk = (lane >> 4) * 8;

  // prologue: stage Q + K/V tile 0
#pragma unroll
  for (int i = 0; i < 2; ++i) {
    int e = (i*256 + t) * 8;
    gl_lds16(Qh + swz(e), QPs + e);
  }
#pragma unroll
  for (int i = 0; i < 2; ++i) {
    int e = (i*256 + t) * 8;
    int x = swz(e);
    gl_lds16(Kh + x, lds + 1*4096 + e);
    gl_lds16(Vh + (size_t)(x >> 6) * Sdim + (x & 63), lds + 3*4096 + e);
  }
  __syncthreads();
  short8 qf0 = *(const short8*)(QPs + lswz(w*16 + fr, fk));
  short8 qf1 = *(const short8*)(QPs + lswz(w*16 + fr, fk + 32));
  __syncthreads();   // all waves done reading Q; QPs becomes P space

  float m_run[4], l_run[4];
  f32x4 oacc[4] = {};
#pragma unroll
  for (int r = 0; r < 4; ++r) { m_run[r] = -1e30f; l_run[r] = 0.f; }

  for (int kt = 0; kt < Sdim/64; ++kt) {
    const int cur = kt & 1;
    uint16_t* Ks = lds + (1 + cur) * 4096;
    uint16_t* Vs = lds + (3 + cur) * 4096;
    // issue next tile's loads into alt buffers (in flight across compute)
    if (kt + 1 < Sdim/64) {
      uint16_t* Kn = lds + (1 + (cur ^ 1)) * 4096;
      uint16_t* Vn = lds + (3 + (cur ^ 1)) * 4096;
#pragma unroll
      for (int i = 0; i < 2; ++i) {
        int e = (i*256 + t) * 8;
        int x = swz(e);
        gl_lds16(Kh + (size_t)(kt + 1) * 4096 + x, Kn + e);
        gl_lds16(Vh + (size_t)(x >> 6) * Sdim + (kt + 1) * 64 + (x & 63), Vn + e);
      }
    }

    // QK^T
    f32x4 sc[4];
    __builtin_amdgcn_s_setprio(1);
#pragma unroll
    for (int kf = 0; kf < 4; ++kf) {
      short8 kb0 = *(const short8*)(Ks + lswz(kf*16 + fr, fk));
      short8 kb1 = *(const short8*)(Ks + lswz(kf*16 + fr, fk + 32));
      f32x4 z = {};
      z = __builtin_amdgcn_mfma_f32_16x16x32_bf16(qf0, kb0, z, 0, 0, 0);
      sc[kf] = __builtin_amdgcn_mfma_f32_16x16x32_bf16(qf1, kb1, z, 0, 0, 0);
    }
    __builtin_amdgcn_s_setprio(0);

    // online softmax: lane holds rows (lane>>4)*4+r, col kf*16+(lane&15)
    float tm[4];
#pragma unroll
    for (int r = 0; r < 4; ++r)
      tm[r] = fmaxf(fmaxf(sc[0][r], sc[1][r]), fmaxf(sc[2][r], sc[3][r]));
#pragma unroll
    for (int d = 1; d < 16; d <<= 1)
#pragma unroll
      for (int r = 0; r < 4; ++r)
        tm[r] = fmaxf(tm[r], __shfl_xor(tm[r], d, 64));
    float al[4], rs[4];
#pragma unroll
    for (int r = 0; r < 4; ++r) {
      float mn = fmaxf(m_run[r], tm[r]);
      al[r] = __expf(m_run[r] - mn);
      m_run[r] = mn;
      rs[r] = 0.f;
    }
#pragma unroll
    for (int kf = 0; kf < 4; ++kf)
#pragma unroll
      for (int r = 0; r < 4; ++r) {
        float p = __expf(sc[kf][r] - m_run[r]);
        sc[kf][r] = p;
        rs[r] += p;
      }
#pragma unroll
    for (int d = 1; d < 16; d <<= 1)
#pragma unroll
      for (int r = 0; r < 4; ++r)
        rs[r] += __shfl_xor(rs[r], d, 64);
#pragma unroll
    for (int r = 0; r < 4; ++r)
      l_run[r] = l_run[r] * al[r] + rs[r];
#pragma unroll
    for (int df = 0; df < 4; ++df)
#pragma unroll
      for (int r = 0; r < 4; ++r)
        oacc[df][r] *= al[r];

    // P: C-layout -> LDS (swizzled, wave-private) -> A-layout
#pragma unroll
    for (int kf = 0; kf < 4; ++kf) {
      const int pcol = kf*16 + fr;
#pragma unroll
      for (int r = 0; r < 4; ++r) {
        const int prow = w*16 + (lane >> 4)*4 + r;
        QPs[prow*64 + (pcol ^ ((prow & 7) << 3))] = f2b(sc[kf][r]);
      }
    }
    asm volatile("s_waitcnt lgkmcnt(0)" ::: "memory");
    __builtin_amdgcn_sched_barrier(0);
    short8 pf0 = *(const short8*)(QPs + lswz(w*16 + fr, fk));
    short8 pf1 = *(const short8*)(QPs + lswz(w*16 + fr, fk + 32));

    // PV: oacc += P * V^T
    __builtin_amdgcn_s_setprio(1);
#pragma unroll
    for (int df = 0; df < 4; ++df) {
      short8 vb0 = *(const short8*)(Vs + lswz(df*16 + fr, fk));
      short8 vb1 = *(const short8*)(Vs + lswz(df*16 + fr, fk + 32));
      oacc[df] = __builtin_amdgcn_mfma_f32_16x16x32_bf16(pf0, vb0, oacc[df], 0, 0, 0);
      oacc[df] = __builtin_amdgcn_mfma_f32_16x16x32_bf16(pf1, vb1, oacc[df], 0, 0, 0);
    }
    __builtin_amdgcn_s_setprio(0);
    __syncthreads();   // drains vmcnt (next tile staged) + protects buffer swap
  }

  // epilogue -> attn_out (B,S,D) bf16
  const int b = bh >> 4, h = bh & 15;
#pragma unroll
  for (int df = 0; df < 4; ++df) {
    const int d = df*16 + fr;
#pragma unroll
    for (int r = 0; r < 4; ++r) {
      const int srow = qt*64 + w*16 + (lane >> 4)*4 + r;
      float o = oacc[df][r] / l_run[r];
      AO[((size_t)b * Sdim + srow) * Ddim + h*DHdim + d] = f2b(o);
    }
  }
}

// ---------------- output projection (f32 out + bias) ----------------
__global__ __launch_bounds__(256, 2) void gemm_out(
    const uint16_t* __restrict__ AOb, const uint16_t* __restrict__ Wo,
    const float* __restrict__ bo, float* __restrict__ out)
{
  __shared__ uint16_t lds[2*128*32];
  const int col0 = blockIdx.x * 128;
  const int row0 = blockIdx.y * 128;
  f32x4 acc[4][4] = {};
  gemm_tile_128(AOb, Wo, Ddim, row0, col0, lds, acc);
  const int lane = threadIdx.x & 63;
  const int w = threadIdx.x >> 6;
  const int wr = (w >> 1) * 64, wc = (w & 1) * 64;
#pragma unroll
  for (int n = 0; n < 4; ++n) {
    const int j = col0 + wc + n*16 + (lane & 15);
    const float bj = bo[j];
#pragma unroll
    for (int m = 0; m < 4; ++m) {
      const int rbase = row0 + wr + m*16 + (lane >> 4) * 4;
#pragma unroll
      for (int r = 0; r < 4; ++r)
        out[(size_t)(rbase + r) * Ddim + j] = acc[m][n][r] + bj;
    }
  }
}

extern "C" void kernel_launch(void* const* d_in, const int* in_sizes, int n_in,
                              void* d_out, int out_size, void* d_ws, size_t ws_size,
                              hipStream_t stream) {
  (void)in_sizes; (void)n_in; (void)out_size; (void)ws_size;
  const float* xq  = (const float*)d_in[0];
  const float* xkv = (const float*)d_in[1];
  const float* Wq  = (const float*)d_in[2];
  const float* bq  = (const float*)d_in[3];
  const float* Wk  = (const float*)d_in[4];
  const float* bk  = (const float*)d_in[5];
  const float* Wv  = (const float*)d_in[6];
  const float* bv  = (const float*)d_in[7];
  const float* Wo  = (const float*)d_in[8];
  const float* bo  = (const float*)d_in[9];
  float* out = (float*)d_out;

  uint16_t* ws = (uint16_t*)d_ws;
  const size_t NX = (size_t)Mdim * Ddim;   // 4194304
  const size_t NW = (size_t)Ddim * Ddim;   // 1048576
  uint16_t* xq_b  = ws; ws += NX;
  uint16_t* xkv_b = ws; ws += NX;
  uint16_t* wq_b  = ws; ws += NW;
  uint16_t* wk_b  = ws; ws += NW;
  uint16_t* wv_b  = ws; ws += NW;
  uint16_t* wo_b  = ws; ws += NW;
  uint16_t* Qb    = ws; ws += NX;
  uint16_t* Kb    = ws; ws += NX;
  uint16_t* Vb    = ws; ws += NX;
  uint16_t* AOb   = ws; ws += NX;

  cvt_bf16<<<NX/1024, 256, 0, stream>>>(xq,  xq_b);
  cvt_bf16<<<NX/1024, 256, 0, stream>>>(xkv, xkv_b);
  cvt_bf16<<<NW/1024, 256, 0, stream>>>(Wq,  wq_b);
  cvt_bf16<<<NW/1024, 256, 0, stream>>>(Wk,  wk_b);
  cvt_bf16<<<NW/1024, 256, 0, stream>>>(Wv,  wv_b);
  cvt_bf16<<<NW/1024, 256, 0, stream>>>(Wo,  wo_b);

  gemm_qkv<<<dim3(24, 32), 256, 0, stream>>>(xq_b, xkv_b, wq_b, wk_b, wv_b,
                                             bq, bk, bv, Qb, Kb, Vb);
  attn<<<dim3(32, 32), 256, 0, stream>>>(Qb, Kb, Vb, AOb);
  gemm_out<<<dim3(8, 32), 256, 0, stream>>>(AOb, wo_b, bo, out);
}

// Round 6
// 221.443 us; speedup vs baseline: 1.4549x; 1.2348x over previous
//
#include <hip/hip_runtime.h>
#include <hip/hip_bf16.h>
#include <stdint.h>

#define Bdim 2
#define Sdim 2048
#define Ddim 1024
#define Hdim 16
#define DHdim 64
#define Mdim (Bdim*Sdim)   // 4096

typedef short short8 __attribute__((ext_vector_type(8)));
typedef float f32x4 __attribute__((ext_vector_type(4)));

__device__ __forceinline__ uint16_t f2b(float f) {
  union { float f; uint32_t u; } c; c.f = f;
  uint32_t u = c.u;
  u += 0x7fffu + ((u >> 16) & 1u);   // RNE
  return (uint16_t)(u >> 16);
}

__device__ __forceinline__ void gl_lds16(const void* g, void* l) {
  __builtin_amdgcn_global_load_lds(
      (const __attribute__((address_space(1))) void*)g,
      (__attribute__((address_space(3))) void*)l, 16, 0, 0);
}

// XOR swizzle for [row][64]-elem bf16 tiles: 16B slot index ^= row&7.
__device__ __forceinline__ int swz(int e) {
  return e ^ (((e >> 6) & 7) << 3);
}
__device__ __forceinline__ int lswz(int row, int col) {
  return row * 64 + (col ^ ((row & 7) << 3));
}
// K-row permutation sigma^-1: makes swapped-QK^T C-layout == PV A-frag layout.
// bits: out5=i5, out4=i3, out3=i2, out2=i4, out1=i1, out0=i0
__device__ __forceinline__ int pik(int i) {
  return (i & 35) | ((i & 8) << 1) | ((i & 4) << 1) | ((i & 16) >> 2);
}

// ---------------- fused f32 -> bf16 conversion (one launch) ----------------
// out segments contiguous: xq(4096 blk) xkv(4096) Wq(1024) Wk Wv Wo
__global__ void cvt_all(const float* __restrict__ a0, const float* __restrict__ a1,
                        const float* __restrict__ a2, const float* __restrict__ a3,
                        const float* __restrict__ a4, const float* __restrict__ a5,
                        uint16_t* __restrict__ o) {
  const int b = blockIdx.x;
  const float* s; int i;
  if      (b <  4096) { s = a0; i = b; }
  else if (b <  8192) { s = a1; i = b - 4096; }
  else if (b <  9216) { s = a2; i = b - 8192; }
  else if (b < 10240) { s = a3; i = b - 9216; }
  else if (b < 11264) { s = a4; i = b - 10240; }
  else                { s = a5; i = b - 11264; }
  const int e = (i * 256 + threadIdx.x) * 4;
  float4 v = *(const float4*)(s + e);
  ushort4 r;
  r.x = f2b(v.x); r.y = f2b(v.y); r.z = f2b(v.z); r.w = f2b(v.w);
  *(ushort4*)(o + (size_t)b * 1024 + threadIdx.x * 4) = r;
}

// ---------------- shared 128x128 GEMM mainloop (C = A * B^T), bf16 ----------------
__device__ __forceinline__ void gemm_tile_128(
    const uint16_t* __restrict__ A, const uint16_t* __restrict__ Bm,
    int K, int row0, int col0, uint16_t* lds, f32x4 acc[4][4])
{
  uint16_t* As = lds;            // [128][32]
  uint16_t* Bs = lds + 128*32;   // [128][32]
  const int t = threadIdx.x;
  const int lane = t & 63;
  const int w = t >> 6;
  const int wr = (w >> 1) * 64;
  const int wc = (w & 1) * 64;
  const int fr = lane & 15;
  const int fk = (lane >> 4) * 8;

  for (int k0 = 0; k0 < K; k0 += 32) {
#pragma unroll
    for (int i = 0; i < 2; ++i) {
      int e = (i*256 + t) * 8;
      int r = e >> 5, c = e & 31;
      gl_lds16(A  + (size_t)(row0 + r) * K + (k0 + c), As + e);
      gl_lds16(Bm + (size_t)(col0 + r) * K + (k0 + c), Bs + e);
    }
    __syncthreads();
    short8 af[4], bf[4];
#pragma unroll
    for (int m = 0; m < 4; ++m)
      af[m] = *(const short8*)(As + (wr + m*16 + fr)*32 + fk);
#pragma unroll
    for (int n = 0; n < 4; ++n)
      bf[n] = *(const short8*)(Bs + (wc + n*16 + fr)*32 + fk);
#pragma unroll
    for (int m = 0; m < 4; ++m)
#pragma unroll
      for (int n = 0; n < 4; ++n)
        acc[m][n] = __builtin_amdgcn_mfma_f32_16x16x32_bf16(af[m], bf[n], acc[m][n], 0, 0, 0);
    __syncthreads();
  }
}

// ---------------- fused QKV projection ----------------
__global__ __launch_bounds__(256, 2) void gemm_qkv(
    const uint16_t* __restrict__ xq, const uint16_t* __restrict__ xkv,
    const uint16_t* __restrict__ Wq, const uint16_t* __restrict__ Wk,
    const uint16_t* __restrict__ Wv,
    const float* __restrict__ bq, const float* __restrict__ bk,
    const float* __restrict__ bv,
    uint16_t* __restrict__ Qo, uint16_t* __restrict__ Ko, uint16_t* __restrict__ Vo)
{
  __shared__ uint16_t lds[2*128*32];
  const int grp  = blockIdx.x >> 3;
  const int col0 = (blockIdx.x & 7) * 128;
  const int row0 = blockIdx.y * 128;
  const uint16_t* A  = (grp == 0) ? xq : xkv;
  const uint16_t* Wm = (grp == 0) ? Wq : (grp == 1) ? Wk : Wv;
  const float* bias  = (grp == 0) ? bq : (grp == 1) ? bk : bv;

  f32x4 acc[4][4] = {};
  gemm_tile_128(A, Wm, Ddim, row0, col0, lds, acc);

  const int lane = threadIdx.x & 63;
  const int w = threadIdx.x >> 6;
  const int wr = (w >> 1) * 64, wc = (w & 1) * 64;

  if (grp == 2) {
    // V -> (B,H,DH,S), packed 4-consecutive-s stores
#pragma unroll
    for (int n = 0; n < 4; ++n) {
      const int j  = col0 + wc + n*16 + (lane & 15);
      const float bj = bias[j];
      const int h = j >> 6, dh = j & 63;
#pragma unroll
      for (int m = 0; m < 4; ++m) {
        const int rbase = row0 + wr + m*16 + (lane >> 4) * 4;
        const int b = rbase >> 11, s = rbase & 2047;
        ushort4 o;
        o.x = f2b(acc[m][n][0] + bj);
        o.y = f2b(acc[m][n][1] + bj);
        o.z = f2b(acc[m][n][2] + bj);
        o.w = f2b(acc[m][n][3] + bj);
        *(ushort4*)(Vo + ((size_t)(b*Hdim + h)) * (DHdim*Sdim) + (size_t)dh * Sdim + s) = o;
      }
    }
  } else {
    uint16_t* out = (grp == 0) ? Qo : Ko;
    const float scale = (grp == 0) ? 0.125f : 1.0f;
#pragma unroll
    for (int n = 0; n < 4; ++n) {
      const int j  = col0 + wc + n*16 + (lane & 15);
      const float bj = bias[j];
      const int h = j >> 6, dh = j & 63;
#pragma unroll
      for (int m = 0; m < 4; ++m) {
        const int rbase = row0 + wr + m*16 + (lane >> 4) * 4;
#pragma unroll
        for (int r = 0; r < 4; ++r) {
          const int i = rbase + r;
          const int b = i >> 11, s = i & 2047;
          float v = (acc[m][n][r] + bj) * scale;
          out[((size_t)(b*Hdim + h)) * (Sdim*DHdim) + (size_t)s * DHdim + dh] = f2b(v);
        }
      }
    }
  }
}

// ---------------- flash attention (swapped QK^T, in-register softmax) ----------------
// grid (32, 32): x = q-tile (64 rows), y = b*H+h. 4 waves x 16 q-rows.
// LDS: T0=Kbuf0, T1=Kbuf1 (aliases Q in prologue), T2=Vbuf0, T3=Vbuf1. 32 KB.
__global__ __launch_bounds__(256, 5) void attn(
    const uint16_t* __restrict__ Q, const uint16_t* __restrict__ K,
    const uint16_t* __restrict__ V, uint16_t* __restrict__ AO)
{
  __shared__ uint16_t lds[4*64*64];
  const int t = threadIdx.x, lane = t & 63, w = t >> 6;
  const int bh = blockIdx.y, qt = blockIdx.x;
  const uint16_t* Qh = Q + (size_t)bh * (Sdim*DHdim) + qt * (64*DHdim);
  const uint16_t* Kh = K + (size_t)bh * (Sdim*DHdim);
  const uint16_t* Vh = V + (size_t)bh * (DHdim*Sdim);
  const int fr = lane & 15, fk = (lane >> 4) * 8;

  // prologue: Q -> T1, K0 -> T0 (row-permuted), V0 -> T2
#pragma unroll
  for (int i = 0; i < 2; ++i) {
    int e = (i*256 + t) * 8;
    gl_lds16(Qh + swz(e), lds + 4096 + e);
  }
#pragma unroll
  for (int i = 0; i < 2; ++i) {
    int e = (i*256 + t) * 8;
    int row = e >> 6, scol = (e & 63) ^ ((row & 7) << 3);
    gl_lds16(Kh + (size_t)pik(row) * 64 + scol, lds + e);
    int x = swz(e);
    gl_lds16(Vh + (size_t)(x >> 6) * Sdim + (x & 63), lds + 2*4096 + e);
  }
  __syncthreads();
  short8 qf0 = *(const short8*)(lds + 4096 + lswz(w*16 + fr, fk));
  short8 qf1 = *(const short8*)(lds + 4096 + lswz(w*16 + fr, fk + 32));
  __syncthreads();   // all waves done reading Q; T1 becomes Kbuf1

  float m_run = -1e30f, l_run = 0.f;
  f32x4 oacc[4] = {};

  for (int kt = 0; kt < Sdim/64; ++kt) {
    const int cur = kt & 1;
    const uint16_t* Ks = lds + cur * 4096;
    const uint16_t* Vs = lds + (2 + cur) * 4096;
    if (kt + 1 < Sdim/64) {
      uint16_t* Kn = lds + (cur ^ 1) * 4096;
      uint16_t* Vn = lds + (2 + (cur ^ 1)) * 4096;
#pragma unroll
      for (int i = 0; i < 2; ++i) {
        int e = (i*256 + t) * 8;
        int row = e >> 6, scol = (e & 63) ^ ((row & 7) << 3);
        gl_lds16(Kh + (size_t)(kt + 1) * 4096 + (size_t)pik(row) * 64 + scol, Kn + e);
        int x = swz(e);
        gl_lds16(Vh + (size_t)(x >> 6) * Sdim + (kt + 1) * 64 + (x & 63), Vn + e);
      }
    }

    // swapped QK^T: sc[kf] = S^T chunk; lane holds q=lane&15, keypos=16kf+(lane>>4)*4+r
    f32x4 sc[4];
    __builtin_amdgcn_s_setprio(1);
#pragma unroll
    for (int kf = 0; kf < 4; ++kf) {
      short8 kb0 = *(const short8*)(Ks + lswz(kf*16 + fr, fk));
      short8 kb1 = *(const short8*)(Ks + lswz(kf*16 + fr, fk + 32));
      f32x4 z = {};
      z = __builtin_amdgcn_mfma_f32_16x16x32_bf16(kb0, qf0, z, 0, 0, 0);
      sc[kf] = __builtin_amdgcn_mfma_f32_16x16x32_bf16(kb1, qf1, z, 0, 0, 0);
    }
    __builtin_amdgcn_s_setprio(0);

    // in-register softmax (per-lane scalar m/l for q=lane&15)
    float t0 = fmaxf(fmaxf(sc[0][0], sc[0][1]), fmaxf(sc[0][2], sc[0][3]));
    float t1 = fmaxf(fmaxf(sc[1][0], sc[1][1]), fmaxf(sc[1][2], sc[1][3]));
    float t2 = fmaxf(fmaxf(sc[2][0], sc[2][1]), fmaxf(sc[2][2], sc[2][3]));
    float t3 = fmaxf(fmaxf(sc[3][0], sc[3][1]), fmaxf(sc[3][2], sc[3][3]));
    float tmax = fmaxf(fmaxf(t0, t1), fmaxf(t2, t3));
    tmax = fmaxf(tmax, __shfl_xor(tmax, 16, 64));
    tmax = fmaxf(tmax, __shfl_xor(tmax, 32, 64));
    if (!__all(tmax - m_run <= 8.0f)) {   // defer-max (T13)
      float mnew = fmaxf(m_run, tmax);
      float al = __expf(m_run - mnew);
      m_run = mnew;
      l_run *= al;
      float alq[4];
#pragma unroll
      for (int r = 0; r < 4; ++r)
        alq[r] = __shfl(al, (lane >> 4)*4 + r, 64);
#pragma unroll
      for (int df = 0; df < 4; ++df)
#pragma unroll
        for (int r = 0; r < 4; ++r)
          oacc[df][r] *= alq[r];
    }
    float rs = 0.f;
#pragma unroll
    for (int kf = 0; kf < 4; ++kf)
#pragma unroll
      for (int r = 0; r < 4; ++r) {
        float p = __expf(sc[kf][r] - m_run);
        sc[kf][r] = p;
        rs += p;
      }
    rs += __shfl_xor(rs, 16, 64);
    rs += __shfl_xor(rs, 32, 64);
    l_run += rs;

    // P repack: C-layout -> PV A-frags, purely per-lane (K rows pre-permuted by pik)
    short8 pf0, pf1;
#pragma unroll
    for (int j = 0; j < 4; ++j) {
      pf0[j]     = (short)f2b(sc[0][j]);
      pf0[4 + j] = (short)f2b(sc[1][j]);
      pf1[j]     = (short)f2b(sc[2][j]);
      pf1[4 + j] = (short)f2b(sc[3][j]);
    }

    // PV: oacc += P * V^T
    __builtin_amdgcn_s_setprio(1);
#pragma unroll
    for (int df = 0; df < 4; ++df) {
      short8 vb0 = *(const short8*)(Vs + lswz(df*16 + fr, fk));
      short8 vb1 = *(const short8*)(Vs + lswz(df*16 + fr, fk + 32));
      oacc[df] = __builtin_amdgcn_mfma_f32_16x16x32_bf16(pf0, vb0, oacc[df], 0, 0, 0);
      oacc[df] = __builtin_amdgcn_mfma_f32_16x16x32_bf16(pf1, vb1, oacc[df], 0, 0, 0);
    }
    __builtin_amdgcn_s_setprio(0);
    __syncthreads();   // drains vmcnt (next tile staged) + protects buffer swap
  }

  // epilogue -> attn_out (B,S,D) bf16
  float linv[4];
#pragma unroll
  for (int r = 0; r < 4; ++r)
    linv[r] = 1.0f / __shfl(l_run, (lane >> 4)*4 + r, 64);
  const int b = bh >> 4, h = bh & 15;
#pragma unroll
  for (int df = 0; df < 4; ++df) {
    const int d = df*16 + fr;
#pragma unroll
    for (int r = 0; r < 4; ++r) {
      const int srow = qt*64 + w*16 + (lane >> 4)*4 + r;
      AO[((size_t)b * Sdim + srow) * Ddim + h*DHdim + d] = f2b(oacc[df][r] * linv[r]);
    }
  }
}

// ---------------- output projection (512 threads, f32 out + bias) ----------------
__global__ __launch_bounds__(512, 2) void gemm_out(
    const uint16_t* __restrict__ AOb, const uint16_t* __restrict__ Wo,
    const float* __restrict__ bo, float* __restrict__ out)
{
  __shared__ uint16_t lds[2*128*32];
  uint16_t* As = lds;
  uint16_t* Bs = lds + 4096;
  const int t = threadIdx.x;
  const int lane = t & 63, w = t >> 6;          // 8 waves: 2 rows x 4 cols
  const int wr = (w >> 2) * 64, wc = (w & 3) * 32;
  const int fr = lane & 15, fk = (lane >> 4) * 8;
  const int col0 = blockIdx.x * 128;
  const int row0 = blockIdx.y * 128;
  f32x4 acc[4][2] = {};

  for (int k0 = 0; k0 < Ddim; k0 += 32) {
    int e = t * 8;
    int r = e >> 5, c = e & 31;
    gl_lds16(AOb + (size_t)(row0 + r) * Ddim + (k0 + c), As + e);
    gl_lds16(Wo  + (size_t)(col0 + r) * Ddim + (k0 + c), Bs + e);
    __syncthreads();
    short8 af[4], bf[2];
#pragma unroll
    for (int m = 0; m < 4; ++m)
      af[m] = *(const short8*)(As + (wr + m*16 + fr)*32 + fk);
#pragma unroll
    for (int n = 0; n < 2; ++n)
      bf[n] = *(const short8*)(Bs + (wc + n*16 + fr)*32 + fk);
#pragma unroll
    for (int m = 0; m < 4; ++m)
#pragma unroll
      for (int n = 0; n < 2; ++n)
        acc[m][n] = __builtin_amdgcn_mfma_f32_16x16x32_bf16(af[m], bf[n], acc[m][n], 0, 0, 0);
    __syncthreads();
  }

#pragma unroll
  for (int n = 0; n < 2; ++n) {
    const int j = col0 + wc + n*16 + fr;
    const float bj = bo[j];
#pragma unroll
    for (int m = 0; m < 4; ++m) {
      const int rbase = row0 + wr + m*16 + (lane >> 4) * 4;
#pragma unroll
      for (int r = 0; r < 4; ++r)
        out[(size_t)(rbase + r) * Ddim + j] = acc[m][n][r] + bj;
    }
  }
}

extern "C" void kernel_launch(void* const* d_in, const int* in_sizes, int n_in,
                              void* d_out, int out_size, void* d_ws, size_t ws_size,
                              hipStream_t stream) {
  (void)in_sizes; (void)n_in; (void)out_size; (void)ws_size;
  const float* xq  = (const float*)d_in[0];
  const float* xkv = (const float*)d_in[1];
  const float* Wq  = (const float*)d_in[2];
  const float* bq  = (const float*)d_in[3];
  const float* Wk  = (const float*)d_in[4];
  const float* bk  = (const float*)d_in[5];
  const float* Wv  = (const float*)d_in[6];
  const float* bv  = (const float*)d_in[7];
  const float* Wo  = (const float*)d_in[8];
  const float* bo  = (const float*)d_in[9];
  float* out = (float*)d_out;

  uint16_t* ws = (uint16_t*)d_ws;
  const size_t NX = (size_t)Mdim * Ddim;   // 4194304
  const size_t NW = (size_t)Ddim * Ddim;   // 1048576
  uint16_t* xq_b  = ws; ws += NX;
  uint16_t* xkv_b = ws; ws += NX;
  uint16_t* wq_b  = ws; ws += NW;
  uint16_t* wk_b  = ws; ws += NW;
  uint16_t* wv_b  = ws; ws += NW;
  uint16_t* wo_b  = ws; ws += NW;
  uint16_t* Qb    = ws; ws += NX;
  uint16_t* Kb    = ws; ws += NX;
  uint16_t* Vb    = ws; ws += NX;
  uint16_t* AOb   = ws; ws += NX;

  cvt_all<<<12288, 256, 0, stream>>>(xq, xkv, Wq, Wk, Wv, Wo, xq_b);

  gemm_qkv<<<dim3(24, 32), 256, 0, stream>>>(xq_b, xkv_b, wq_b, wk_b, wv_b,
                                             bq, bk, bv, Qb, Kb, Vb);
  attn<<<dim3(32, 32), 256, 0, stream>>>(Qb, Kb, Vb, AOb);
  gemm_out<<<dim3(8, 32), 512, 0, stream>>>(AOb, wo_b, bo, out);
}

// Round 7
// 214.033 us; speedup vs baseline: 1.5052x; 1.0346x over previous
//
#include <hip/hip_runtime.h>
#include <hip/hip_bf16.h>
#include <stdint.h>

#define Bdim 2
#define Sdim 2048
#define Ddim 1024
#define Hdim 16
#define DHdim 64
#define Mdim (Bdim*Sdim)   // 4096

typedef short short8 __attribute__((ext_vector_type(8)));
typedef float f32x4 __attribute__((ext_vector_type(4)));

__device__ __forceinline__ uint16_t f2b(float f) {
  union { float f; uint32_t u; } c; c.f = f;
  uint32_t u = c.u;
  u += 0x7fffu + ((u >> 16) & 1u);   // RNE
  return (uint16_t)(u >> 16);
}

// packed f32x2 -> bf16x2 (RNE), single instruction
__device__ __forceinline__ uint32_t cvtpk(float lo, float hi) {
  uint32_t r;
  asm("v_cvt_pk_bf16_f32 %0, %1, %2" : "=v"(r) : "v"(lo), "v"(hi));
  return r;
}
// 2^x, native
__device__ __forceinline__ float exp2_fast(float x) {
  float r;
  asm("v_exp_f32 %0, %1" : "=v"(r) : "v"(x));
  return r;
}

__device__ __forceinline__ void gl_lds16(const void* g, void* l) {
  __builtin_amdgcn_global_load_lds(
      (const __attribute__((address_space(1))) void*)g,
      (__attribute__((address_space(3))) void*)l, 16, 0, 0);
}

// XOR swizzle for [row][64]-elem bf16 tiles: 16B slot index ^= row&7.
__device__ __forceinline__ int swz(int e) {
  return e ^ (((e >> 6) & 7) << 3);
}
__device__ __forceinline__ int lswz(int row, int col) {
  return row * 64 + (col ^ ((row & 7) << 3));
}
// K-row permutation sigma^-1: makes swapped-QK^T C-layout == PV A-frag layout.
__device__ __forceinline__ int pik(int i) {
  return (i & 35) | ((i & 8) << 1) | ((i & 4) << 1) | ((i & 16) >> 2);
}

// ---------------- fused f32 -> bf16 conversion (one launch) ----------------
__global__ void cvt_all(const float* __restrict__ a0, const float* __restrict__ a1,
                        const float* __restrict__ a2, const float* __restrict__ a3,
                        const float* __restrict__ a4, const float* __restrict__ a5,
                        uint16_t* __restrict__ o) {
  const int b = blockIdx.x;
  const float* s; int i;
  if      (b <  4096) { s = a0; i = b; }
  else if (b <  8192) { s = a1; i = b - 4096; }
  else if (b <  9216) { s = a2; i = b - 8192; }
  else if (b < 10240) { s = a3; i = b - 9216; }
  else if (b < 11264) { s = a4; i = b - 10240; }
  else                { s = a5; i = b - 11264; }
  const int e = (i * 256 + threadIdx.x) * 4;
  float4 v = *(const float4*)(s + e);
  ushort4 r;
  r.x = f2b(v.x); r.y = f2b(v.y); r.z = f2b(v.z); r.w = f2b(v.w);
  *(ushort4*)(o + (size_t)b * 1024 + threadIdx.x * 4) = r;
}

// ---------------- 128x128 GEMM mainloop, LDS double-buffered ----------------
// C = A * B^T. A: MxK, Bm: NxK, row-major bf16. BK=32. 256 threads (2x2 waves).
// lds: 2 buffers x (As 4096 + Bs 4096) elems = 32 KB.
__device__ __forceinline__ void gemm_tile_128(
    const uint16_t* __restrict__ A, const uint16_t* __restrict__ Bm,
    int K, int row0, int col0, uint16_t* lds, f32x4 acc[4][4])
{
  const int t = threadIdx.x;
  const int lane = t & 63;
  const int w = t >> 6;
  const int wr = (w >> 1) * 64;
  const int wc = (w & 1) * 64;
  const int fr = lane & 15;
  const int fk = (lane >> 4) * 8;

  auto stage = [&](int k0, int buf) {
#pragma unroll
    for (int i = 0; i < 2; ++i) {
      int e = (i*256 + t) * 8;
      int r = e >> 5, c = e & 31;
      gl_lds16(A  + (size_t)(row0 + r) * K + (k0 + c), lds + buf*8192 + e);
      gl_lds16(Bm + (size_t)(col0 + r) * K + (k0 + c), lds + buf*8192 + 4096 + e);
    }
  };

  stage(0, 0);
  __syncthreads();   // drain prologue loads
  for (int k0 = 0; k0 < K; k0 += 32) {
    const int cur = (k0 >> 5) & 1;
    if (k0 + 32 < K) stage(k0 + 32, cur ^ 1);   // prefetch next, in flight across compute
    const uint16_t* As = lds + cur*8192;
    const uint16_t* Bs = lds + cur*8192 + 4096;
    short8 af[4], bf[4];
#pragma unroll
    for (int m = 0; m < 4; ++m)
      af[m] = *(const short8*)(As + (wr + m*16 + fr)*32 + fk);
#pragma unroll
    for (int n = 0; n < 4; ++n)
      bf[n] = *(const short8*)(Bs + (wc + n*16 + fr)*32 + fk);
#pragma unroll
    for (int m = 0; m < 4; ++m)
#pragma unroll
      for (int n = 0; n < 4; ++n)
        acc[m][n] = __builtin_amdgcn_mfma_f32_16x16x32_bf16(af[m], bf[n], acc[m][n], 0, 0, 0);
    __syncthreads();   // drains prefetch vmcnt + protects buffer swap
  }
}

// ---------------- fused QKV projection ----------------
__global__ __launch_bounds__(256, 2) void gemm_qkv(
    const uint16_t* __restrict__ xq, const uint16_t* __restrict__ xkv,
    const uint16_t* __restrict__ Wq, const uint16_t* __restrict__ Wk,
    const uint16_t* __restrict__ Wv,
    const float* __restrict__ bq, const float* __restrict__ bk,
    const float* __restrict__ bv,
    uint16_t* __restrict__ Qo, uint16_t* __restrict__ Ko, uint16_t* __restrict__ Vo)
{
  __shared__ uint16_t lds[2*8192];
  const int grp  = blockIdx.x >> 3;
  const int col0 = (blockIdx.x & 7) * 128;
  const int row0 = blockIdx.y * 128;
  const uint16_t* A  = (grp == 0) ? xq : xkv;
  const uint16_t* Wm = (grp == 0) ? Wq : (grp == 1) ? Wk : Wv;
  const float* bias  = (grp == 0) ? bq : (grp == 1) ? bk : bv;

  f32x4 acc[4][4] = {};
  gemm_tile_128(A, Wm, Ddim, row0, col0, lds, acc);

  const int lane = threadIdx.x & 63;
  const int w = threadIdx.x >> 6;
  const int wr = (w >> 1) * 64, wc = (w & 1) * 64;

  if (grp == 2) {
    // V -> (B,H,DH,S), packed 4-consecutive-s stores
#pragma unroll
    for (int n = 0; n < 4; ++n) {
      const int j  = col0 + wc + n*16 + (lane & 15);
      const float bj = bias[j];
      const int h = j >> 6, dh = j & 63;
#pragma unroll
      for (int m = 0; m < 4; ++m) {
        const int rbase = row0 + wr + m*16 + (lane >> 4) * 4;
        const int b = rbase >> 11, s = rbase & 2047;
        ushort4 o;
        o.x = f2b(acc[m][n][0] + bj);
        o.y = f2b(acc[m][n][1] + bj);
        o.z = f2b(acc[m][n][2] + bj);
        o.w = f2b(acc[m][n][3] + bj);
        *(ushort4*)(Vo + ((size_t)(b*Hdim + h)) * (DHdim*Sdim) + (size_t)dh * Sdim + s) = o;
      }
    }
  } else {
    uint16_t* out = (grp == 0) ? Qo : Ko;
    // Q pre-scaled by (1/sqrt(DH)) * log2(e): softmax done in exp2 domain.
    const float scale = (grp == 0) ? 0.18033688011112042f : 1.0f;
#pragma unroll
    for (int n = 0; n < 4; ++n) {
      const int j  = col0 + wc + n*16 + (lane & 15);
      const float bj = bias[j];
      const int h = j >> 6, dh = j & 63;
#pragma unroll
      for (int m = 0; m < 4; ++m) {
        const int rbase = row0 + wr + m*16 + (lane >> 4) * 4;
#pragma unroll
        for (int r = 0; r < 4; ++r) {
          const int i = rbase + r;
          const int b = i >> 11, s = i & 2047;
          float v = (acc[m][n][r] + bj) * scale;
          out[((size_t)(b*Hdim + h)) * (Sdim*DHdim) + (size_t)s * DHdim + dh] = f2b(v);
        }
      }
    }
  }
}

// ---------------- flash attention (swapped QK^T, in-register softmax) ----------------
// grid (32, 32): x = q-tile (64 rows), y = b*H+h. 4 waves x 16 q-rows.
// Scores arrive in log2 domain (Q pre-scaled); softmax uses bare v_exp_f32.
__global__ __launch_bounds__(256, 5) void attn(
    const uint16_t* __restrict__ Q, const uint16_t* __restrict__ K,
    const uint16_t* __restrict__ V, uint16_t* __restrict__ AO)
{
  __shared__ uint16_t lds[4*64*64];
  const int t = threadIdx.x, lane = t & 63, w = t >> 6;
  const int bh = blockIdx.y, qt = blockIdx.x;
  const uint16_t* Qh = Q + (size_t)bh * (Sdim*DHdim) + qt * (64*DHdim);
  const uint16_t* Kh = K + (size_t)bh * (Sdim*DHdim);
  const uint16_t* Vh = V + (size_t)bh * (DHdim*Sdim);
  const int fr = lane & 15, fk = (lane >> 4) * 8;

  // prologue: Q -> T1, K0 -> T0 (row-permuted), V0 -> T2
#pragma unroll
  for (int i = 0; i < 2; ++i) {
    int e = (i*256 + t) * 8;
    gl_lds16(Qh + swz(e), lds + 4096 + e);
  }
#pragma unroll
  for (int i = 0; i < 2; ++i) {
    int e = (i*256 + t) * 8;
    int row = e >> 6, scol = (e & 63) ^ ((row & 7) << 3);
    gl_lds16(Kh + (size_t)pik(row) * 64 + scol, lds + e);
    int x = swz(e);
    gl_lds16(Vh + (size_t)(x >> 6) * Sdim + (x & 63), lds + 2*4096 + e);
  }
  __syncthreads();
  short8 qf0 = *(const short8*)(lds + 4096 + lswz(w*16 + fr, fk));
  short8 qf1 = *(const short8*)(lds + 4096 + lswz(w*16 + fr, fk + 32));
  __syncthreads();   // all waves done reading Q; T1 becomes Kbuf1

  float m_run = -1e30f, l_run = 0.f;
  f32x4 oacc[4] = {};

  for (int kt = 0; kt < Sdim/64; ++kt) {
    const int cur = kt & 1;
    const uint16_t* Ks = lds + cur * 4096;
    const uint16_t* Vs = lds + (2 + cur) * 4096;
    if (kt + 1 < Sdim/64) {
      uint16_t* Kn = lds + (cur ^ 1) * 4096;
      uint16_t* Vn = lds + (2 + (cur ^ 1)) * 4096;
#pragma unroll
      for (int i = 0; i < 2; ++i) {
        int e = (i*256 + t) * 8;
        int row = e >> 6, scol = (e & 63) ^ ((row & 7) << 3);
        gl_lds16(Kh + (size_t)(kt + 1) * 4096 + (size_t)pik(row) * 64 + scol, Kn + e);
        int x = swz(e);
        gl_lds16(Vh + (size_t)(x >> 6) * Sdim + (kt + 1) * 64 + (x & 63), Vn + e);
      }
    }

    // swapped QK^T: lane holds q=lane&15, keypos=16kf+(lane>>4)*4+r (log2 domain)
    f32x4 sc[4];
    __builtin_amdgcn_s_setprio(1);
#pragma unroll
    for (int kf = 0; kf < 4; ++kf) {
      short8 kb0 = *(const short8*)(Ks + lswz(kf*16 + fr, fk));
      short8 kb1 = *(const short8*)(Ks + lswz(kf*16 + fr, fk + 32));
      f32x4 z = {};
      z = __builtin_amdgcn_mfma_f32_16x16x32_bf16(kb0, qf0, z, 0, 0, 0);
      sc[kf] = __builtin_amdgcn_mfma_f32_16x16x32_bf16(kb1, qf1, z, 0, 0, 0);
    }
    __builtin_amdgcn_s_setprio(0);

    // in-register softmax (exp2 domain)
    float t0 = fmaxf(fmaxf(sc[0][0], sc[0][1]), fmaxf(sc[0][2], sc[0][3]));
    float t1 = fmaxf(fmaxf(sc[1][0], sc[1][1]), fmaxf(sc[1][2], sc[1][3]));
    float t2 = fmaxf(fmaxf(sc[2][0], sc[2][1]), fmaxf(sc[2][2], sc[2][3]));
    float t3 = fmaxf(fmaxf(sc[3][0], sc[3][1]), fmaxf(sc[3][2], sc[3][3]));
    float tmax = fmaxf(fmaxf(t0, t1), fmaxf(t2, t3));
    tmax = fmaxf(tmax, __shfl_xor(tmax, 16, 64));
    tmax = fmaxf(tmax, __shfl_xor(tmax, 32, 64));
    if (!__all(tmax - m_run <= 8.0f)) {   // defer-max; deferred P bounded by 2^8
      float mnew = fmaxf(m_run, tmax);
      float al = exp2_fast(m_run - mnew);
      m_run = mnew;
      l_run *= al;
      float alq[4];
#pragma unroll
      for (int r = 0; r < 4; ++r)
        alq[r] = __shfl(al, (lane >> 4)*4 + r, 64);
#pragma unroll
      for (int df = 0; df < 4; ++df)
#pragma unroll
        for (int r = 0; r < 4; ++r)
          oacc[df][r] *= alq[r];
    }
    float rs = 0.f;
#pragma unroll
    for (int kf = 0; kf < 4; ++kf)
#pragma unroll
      for (int r = 0; r < 4; ++r) {
        float p = exp2_fast(sc[kf][r] - m_run);
        sc[kf][r] = p;
        rs += p;
      }
    rs += __shfl_xor(rs, 16, 64);
    rs += __shfl_xor(rs, 32, 64);
    l_run += rs;

    // P repack: C-layout -> PV A-frags via packed cvt (8 instrs)
    int4 pw0, pw1;
    pw0.x = cvtpk(sc[0][0], sc[0][1]);
    pw0.y = cvtpk(sc[0][2], sc[0][3]);
    pw0.z = cvtpk(sc[1][0], sc[1][1]);
    pw0.w = cvtpk(sc[1][2], sc[1][3]);
    pw1.x = cvtpk(sc[2][0], sc[2][1]);
    pw1.y = cvtpk(sc[2][2], sc[2][3]);
    pw1.z = cvtpk(sc[3][0], sc[3][1]);
    pw1.w = cvtpk(sc[3][2], sc[3][3]);
    short8 pf0 = *(short8*)&pw0;
    short8 pf1 = *(short8*)&pw1;

    // PV: oacc += P * V^T
    __builtin_amdgcn_s_setprio(1);
#pragma unroll
    for (int df = 0; df < 4; ++df) {
      short8 vb0 = *(const short8*)(Vs + lswz(df*16 + fr, fk));
      short8 vb1 = *(const short8*)(Vs + lswz(df*16 + fr, fk + 32));
      oacc[df] = __builtin_amdgcn_mfma_f32_16x16x32_bf16(pf0, vb0, oacc[df], 0, 0, 0);
      oacc[df] = __builtin_amdgcn_mfma_f32_16x16x32_bf16(pf1, vb1, oacc[df], 0, 0, 0);
    }
    __builtin_amdgcn_s_setprio(0);
    __syncthreads();   // drains vmcnt (next tile staged) + protects buffer swap
  }

  // epilogue -> attn_out (B,S,D) bf16
  float linv[4];
#pragma unroll
  for (int r = 0; r < 4; ++r)
    linv[r] = 1.0f / __shfl(l_run, (lane >> 4)*4 + r, 64);
  const int b = bh >> 4, h = bh & 15;
#pragma unroll
  for (int df = 0; df < 4; ++df) {
    const int d = df*16 + fr;
#pragma unroll
    for (int r = 0; r < 4; ++r) {
      const int srow = qt*64 + w*16 + (lane >> 4)*4 + r;
      AO[((size_t)b * Sdim + srow) * Ddim + h*DHdim + d] = f2b(oacc[df][r] * linv[r]);
    }
  }
}

// ---------------- output projection (512 threads, dbuf, f32 out + bias) ----------------
__global__ __launch_bounds__(512, 2) void gemm_out(
    const uint16_t* __restrict__ AOb, const uint16_t* __restrict__ Wo,
    const float* __restrict__ bo, float* __restrict__ out)
{
  __shared__ uint16_t lds[2*8192];
  const int t = threadIdx.x;
  const int lane = t & 63, w = t >> 6;          // 8 waves: 2 rows x 4 cols
  const int wr = (w >> 2) * 64, wc = (w & 3) * 32;
  const int fr = lane & 15, fk = (lane >> 4) * 8;
  const int col0 = blockIdx.x * 128;
  const int row0 = blockIdx.y * 128;
  f32x4 acc[4][2] = {};

  auto stage = [&](int k0, int buf) {
    int e = t * 8;
    int r = e >> 5, c = e & 31;
    gl_lds16(AOb + (size_t)(row0 + r) * Ddim + (k0 + c), lds + buf*8192 + e);
    gl_lds16(Wo  + (size_t)(col0 + r) * Ddim + (k0 + c), lds + buf*8192 + 4096 + e);
  };

  stage(0, 0);
  __syncthreads();
  for (int k0 = 0; k0 < Ddim; k0 += 32) {
    const int cur = (k0 >> 5) & 1;
    if (k0 + 32 < Ddim) stage(k0 + 32, cur ^ 1);
    const uint16_t* As = lds + cur*8192;
    const uint16_t* Bs = lds + cur*8192 + 4096;
    short8 af[4], bf[2];
#pragma unroll
    for (int m = 0; m < 4; ++m)
      af[m] = *(const short8*)(As + (wr + m*16 + fr)*32 + fk);
#pragma unroll
    for (int n = 0; n < 2; ++n)
      bf[n] = *(const short8*)(Bs + (wc + n*16 + fr)*32 + fk);
#pragma unroll
    for (int m = 0; m < 4; ++m)
#pragma unroll
      for (int n = 0; n < 2; ++n)
        acc[m][n] = __builtin_amdgcn_mfma_f32_16x16x32_bf16(af[m], bf[n], acc[m][n], 0, 0, 0);
    __syncthreads();
  }

#pragma unroll
  for (int n = 0; n < 2; ++n) {
    const int j = col0 + wc + n*16 + fr;
    const float bj = bo[j];
#pragma unroll
    for (int m = 0; m < 4; ++m) {
      const int rbase = row0 + wr + m*16 + (lane >> 4) * 4;
#pragma unroll
      for (int r = 0; r < 4; ++r)
        out[(size_t)(rbase + r) * Ddim + j] = acc[m][n][r] + bj;
    }
  }
}

extern "C" void kernel_launch(void* const* d_in, const int* in_sizes, int n_in,
                              void* d_out, int out_size, void* d_ws, size_t ws_size,
                              hipStream_t stream) {
  (void)in_sizes; (void)n_in; (void)out_size; (void)ws_size;
  const float* xq  = (const float*)d_in[0];
  const float* xkv = (const float*)d_in[1];
  const float* Wq  = (const float*)d_in[2];
  const float* bq  = (const float*)d_in[3];
  const float* Wk  = (const float*)d_in[4];
  const float* bk  = (const float*)d_in[5];
  const float* Wv  = (const float*)d_in[6];
  const float* bv  = (const float*)d_in[7];
  const float* Wo  = (const float*)d_in[8];
  const float* bo  = (const float*)d_in[9];
  float* out = (float*)d_out;

  uint16_t* ws = (uint16_t*)d_ws;
  const size_t NX = (size_t)Mdim * Ddim;   // 4194304
  const size_t NW = (size_t)Ddim * Ddim;   // 1048576
  uint16_t* xq_b  = ws; ws += NX;
  uint16_t* xkv_b = ws; ws += NX;
  uint16_t* wq_b  = ws; ws += NW;
  uint16_t* wk_b  = ws; ws += NW;
  uint16_t* wv_b  = ws; ws += NW;
  uint16_t* wo_b  = ws; ws += NW;
  uint16_t* Qb    = ws; ws += NX;
  uint16_t* Kb    = ws; ws += NX;
  uint16_t* Vb    = ws; ws += NX;
  uint16_t* AOb   = ws; ws += NX;

  cvt_all<<<12288, 256, 0, stream>>>(xq, xkv, Wq, Wk, Wv, Wo, xq_b);

  gemm_qkv<<<dim3(24, 32), 256, 0, stream>>>(xq_b, xkv_b, wq_b, wk_b, wv_b,
                                             bq, bk, bv, Qb, Kb, Vb);
  attn<<<dim3(32, 32), 256, 0, stream>>>(Qb, Kb, Vb, AOb);
  gemm_out<<<dim3(8, 32), 512, 0, stream>>>(AOb, wo_b, bo, out);
}